// Round 4
// baseline (3700.860 us; speedup 1.0000x reference)
//
#include <hip/hip_runtime.h>

typedef unsigned int uint;
typedef unsigned short ushort;

typedef __attribute__((ext_vector_type(8))) __bf16 bf16x8;
typedef __attribute__((ext_vector_type(4))) float f32x4;

#define B_ 64
#define S_ 256
#define D_ 512
#define H_ 8
#define DFF_ 2048
#define V_ 128
#define L_ 6
#define BS_ (B_ * S_)

__device__ __forceinline__ float blo(uint u) { return __uint_as_float(u << 16); }
__device__ __forceinline__ float bhi(uint u) { return __uint_as_float(u & 0xffff0000u); }
__device__ __forceinline__ float b2f(ushort u) { return __uint_as_float(((uint)u) << 16); }
__device__ __forceinline__ ushort f2b(float f) {
  uint u = __float_as_uint(f);
  return (ushort)((u + 0x7fffu + ((u >> 16) & 1u)) >> 16);  // RTNE
}
__device__ __forceinline__ uint pack2(float a, float b) {
  return (uint)f2b(a) | ((uint)f2b(b) << 16);
}

// -------- embedding: x16 = bf16(emb[tgt] + pos); emb/pos are fp32 ----------
__global__ __launch_bounds__(256) void embed_kernel(
    const int* __restrict__ tgt, const float* __restrict__ emb,
    const float* __restrict__ pos, ushort* __restrict__ x16) {
  int p = blockIdx.x * 256 + threadIdx.x;  // pair index; 256 pairs per row
  int row = p >> 8;
  int d2 = p & 255;
  int s = row & (S_ - 1);
  int tok = tgt[row];
  float2 e = ((const float2*)emb)[tok * 256 + d2];
  float2 pp = ((const float2*)pos)[s * 256 + d2];
  ((uint*)x16)[p] = pack2(e.x + pp.x, e.y + pp.y);
}

// ---- small fp32 GEMM: C[64][512] = A[64][512] . W[512][512]^T + bias ------
__global__ __launch_bounds__(256) void small_gemm(
    const float* __restrict__ A, const float* __restrict__ W,
    const float* __restrict__ bias, float* __restrict__ C) {
  int t = blockIdx.x * 256 + threadIdx.x;  // 0..32767
  int m = t >> 9, n = t & 511;
  const float4* ap = (const float4*)(A + (size_t)m * 512);
  const float4* wp = (const float4*)(W + (size_t)n * 512);
  float acc = bias[n];
  for (int k4 = 0; k4 < 128; ++k4) {
    float4 a = ap[k4], w = wp[k4];
    acc += a.x * w.x + a.y * w.y + a.z * w.z + a.w * w.w;
  }
  C[t] = acc;
}

// --- MFMA GEMM: C = A_bf16[.,K](stride As) . W_fp32(stride Ws)[N][K]^T -----
// W is converted fp32->bf16 during staging (2x float4 -> 8 bf16 per lane).
// MODE 0: C=bf16(acc+bias)  1: relu  2: bf16 C+=acc (RMW)  3: fp32 C=acc+bias
// 128x128 tile, BK=32, 4 waves 2x2, each 64x64 = 4x4 MFMA 16x16x32 tiles.
// A-frag a[j]=A[m=lane&15][k=(lane>>4)*8+j]; B-frag b[j]=W[n=lane&15][k=same];
// C/D: reg r -> row=(lane>>4)*4+r, col=lane&15 (m89/m91-verified).
template <int MODE>
__global__ __launch_bounds__(256) void gemm_bt(
    const ushort* __restrict__ A, const float* __restrict__ W,
    const float* __restrict__ bias, void* __restrict__ Cv, int N, int K,
    int As, int Ws, int Cs) {
  __shared__ ushort la[128 * 32];
  __shared__ ushort lb[128 * 32];
  const int tid = threadIdx.x;
  const int wv = tid >> 6, lane = tid & 63;
  const int m0 = blockIdx.y << 7, n0 = blockIdx.x << 7;
  const int wm = (wv >> 1) << 6, wn = (wv & 1) << 6;
  const int tr = lane & 15, tq = lane >> 4;

  // wave wv covers linear short range [wv*1024, wv*1024+1024): 32 rows x 32 k
  const int lin0 = wv * 1024 + lane * 8;
  const int lin1 = lin0 + 512;
  const int am0 = lin0 >> 5, ac0 = lin0 & 31;
  const int am1 = lin1 >> 5, ac1 = lin1 & 31;

  const ushort* pa0 = A + (size_t)(m0 + am0) * As + ac0;
  const ushort* pa1 = A + (size_t)(m0 + am1) * As + ac1;
  const float* pb0 = W + (size_t)(n0 + am0) * Ws + ac0;
  const float* pb1 = W + (size_t)(n0 + am1) * Ws + ac1;

  f32x4 acc[4][4];
#pragma unroll
  for (int i = 0; i < 4; ++i)
#pragma unroll
    for (int j = 0; j < 4; ++j) acc[i][j] = (f32x4)(0.f);

  const int KT = K >> 5;
  for (int kt = 0; kt < KT; ++kt) {
    const int kb = kt << 5;
    uint4 ra0 = *(const uint4*)(pa0 + kb);
    uint4 ra1 = *(const uint4*)(pa1 + kb);
    float4 f00 = *(const float4*)(pb0 + kb);
    float4 f01 = *(const float4*)(pb0 + kb + 4);
    float4 f10 = *(const float4*)(pb1 + kb);
    float4 f11 = *(const float4*)(pb1 + kb + 4);
    uint4 rb0 = make_uint4(pack2(f00.x, f00.y), pack2(f00.z, f00.w),
                           pack2(f01.x, f01.y), pack2(f01.z, f01.w));
    uint4 rb1 = make_uint4(pack2(f10.x, f10.y), pack2(f10.z, f10.w),
                           pack2(f11.x, f11.y), pack2(f11.z, f11.w));
    __syncthreads();  // protect prior iteration's LDS reads
    *(uint4*)&la[lin0] = ra0;
    *(uint4*)&la[lin1] = ra1;
    *(uint4*)&lb[lin0] = rb0;
    *(uint4*)&lb[lin1] = rb1;
    __syncthreads();
    bf16x8 av[4], bv[4];
#pragma unroll
    for (int i = 0; i < 4; ++i)
      av[i] = *(const bf16x8*)&la[(wm + i * 16 + tr) * 32 + tq * 8];
#pragma unroll
    for (int j = 0; j < 4; ++j)
      bv[j] = *(const bf16x8*)&lb[(wn + j * 16 + tr) * 32 + tq * 8];
#pragma unroll
    for (int i = 0; i < 4; ++i)
#pragma unroll
      for (int j = 0; j < 4; ++j)
        acc[i][j] =
            __builtin_amdgcn_mfma_f32_16x16x32_bf16(av[i], bv[j], acc[i][j], 0, 0, 0);
  }

#pragma unroll
  for (int j = 0; j < 4; ++j) {
    const int gn = n0 + wn + j * 16 + tr;
    float bj = 0.f;
    if (MODE != 2) bj = bias[gn];
#pragma unroll
    for (int i = 0; i < 4; ++i) {
      const int gmb = m0 + wm + i * 16 + tq * 4;
#pragma unroll
      for (int r = 0; r < 4; ++r) {
        const size_t idx = (size_t)(gmb + r) * Cs + gn;
        float v = acc[i][j][r] + bj;
        if (MODE == 1) v = fmaxf(v, 0.f);
        if (MODE == 3)
          ((float*)Cv)[idx] = v;
        else if (MODE == 2) {
          ushort* C = (ushort*)Cv;
          C[idx] = f2b(b2f(C[idx]) + acc[i][j][r]);  // K-split accumulate
        } else
          ((ushort*)Cv)[idx] = f2b(v);
      }
    }
  }
}

// ------- causal self-attention, one (b,h) per block, IN-PLACE over q-slice ---
__global__ __launch_bounds__(256) void attn_kernel(ushort* qkv) {
  __shared__ uint ks[8192];  // 256 keys x 32 uint (64 bf16)
  __shared__ uint vs[8192];
  const int h = blockIdx.x, b = blockIdx.y;
  const int t = threadIdx.x;  // q row
  uint* q32 = (uint*)qkv;     // row stride 1536 shorts = 768 uints
#pragma unroll
  for (int i = 0; i < 32; ++i) {
    int lin = i * 256 + t;
    int row = lin >> 5, cp = lin & 31;
    size_t base = (size_t)(b * S_ + row) * 768 + h * 32;
    ks[lin] = q32[base + 256 + cp];  // K region: uints [256,512)
    vs[lin] = q32[base + 512 + cp];  // V region: uints [512,768)
  }
  float q[64];
  const size_t qb = (size_t)(b * S_ + t) * 768 + h * 32;
  {
    const float SC = 0.18033688011112042f;  // log2(e)/sqrt(64)
#pragma unroll
    for (int p = 0; p < 32; ++p) {
      uint u = q32[qb + p];
      q[2 * p] = blo(u) * SC;
      q[2 * p + 1] = bhi(u) * SC;
    }
  }
  __syncthreads();
  float acc[64];
#pragma unroll
  for (int d = 0; d < 64; ++d) acc[d] = 0.f;
  float l = 0.f;
  for (int kk = 0; kk <= t; ++kk) {  // causal
    const uint* kr = &ks[kk * 32];
    float s = 0.f;
#pragma unroll
    for (int p = 0; p < 32; ++p) {
      uint u = kr[p];
      s += q[2 * p] * blo(u) + q[2 * p + 1] * bhi(u);
    }
    float e = exp2f(s);  // scores O(1): no max-subtraction needed
    l += e;
    const uint* vr = &vs[kk * 32];
#pragma unroll
    for (int p = 0; p < 32; ++p) {
      uint u = vr[p];
      acc[2 * p] += e * blo(u);
      acc[2 * p + 1] += e * bhi(u);
    }
  }
  float inv = 1.f / l;
#pragma unroll
  for (int p = 0; p < 32; ++p)
    q32[qb + p] = pack2(acc[2 * p] * inv, acc[2 * p + 1] * inv);
}

// -------- LayerNorm: x16 = bf16(LN(x16 + delta) * sc + bi), in place --------
// DM 0: delta bf16 pairs, row stride DsU uints. DM 1: delta fp32 per-batch
// broadcast (row r -> batch r>>8). sc/bi fp32.
template <int DM>
__global__ __launch_bounds__(256) void ln_kernel(
    ushort* __restrict__ x16, const void* __restrict__ delta, int DsU,
    const float* __restrict__ sc, const float* __restrict__ bi) {
  const int r = blockIdx.x, t = threadIdx.x;
  const int lane = t & 63, wv = t >> 6;
  uint* xr = (uint*)x16 + (size_t)r * 256;
  uint xu = xr[t];
  float d0, d1;
  if (DM == 0) {
    uint du = ((const uint*)delta)[(size_t)r * DsU + t];
    d0 = blo(du);
    d1 = bhi(du);
  } else {
    float2 dv = ((const float2*)delta)[(size_t)(r >> 8) * 256 + t];
    d0 = dv.x;
    d1 = dv.y;
  }
  float v0 = blo(xu) + d0, v1 = bhi(xu) + d1;
  float sm = v0 + v1, sq = v0 * v0 + v1 * v1;
#pragma unroll
  for (int o = 32; o > 0; o >>= 1) {
    sm += __shfl_xor(sm, o, 64);
    sq += __shfl_xor(sq, o, 64);
  }
  __shared__ float red[4][2];
  if (lane == 0) {
    red[wv][0] = sm;
    red[wv][1] = sq;
  }
  __syncthreads();
  sm = red[0][0] + red[1][0] + red[2][0] + red[3][0];
  sq = red[0][1] + red[1][1] + red[2][1] + red[3][1];
  float mean = sm * (1.f / 512.f);
  float var = sq * (1.f / 512.f) - mean * mean;
  float rs = rsqrtf(var + 1e-5f);
  float2 s2 = ((const float2*)sc)[t];
  float2 b2 = ((const float2*)bi)[t];
  float y0 = (v0 - mean) * rs * s2.x + b2.x;
  float y1 = (v1 - mean) * rs * s2.y + b2.y;
  xr[t] = pack2(y0, y1);
}

extern "C" void kernel_launch(void* const* d_in, const int* in_sizes, int n_in,
                              void* d_out, int out_size, void* d_ws,
                              size_t ws_size, hipStream_t stream) {
  (void)in_sizes; (void)n_in; (void)out_size; (void)ws_size;
  const float* z = (const float*)d_in[0];
  const int* tgt = (const int*)d_in[1];
  const float* emb = (const float*)d_in[2];
  const float* pos = (const float*)d_in[3];
  const float* projw = (const float*)d_in[4];
  const float* projb = (const float*)d_in[5];
  const float* saw = (const float*)d_in[6];
  const float* sab = (const float*)d_in[7];
  const float* saow = (const float*)d_in[8];
  const float* saob = (const float*)d_in[9];
  const float* caw = (const float*)d_in[10];
  const float* cab = (const float*)d_in[11];
  const float* caow = (const float*)d_in[12];
  const float* caob = (const float*)d_in[13];
  const float* ln1s = (const float*)d_in[14];
  const float* ln1b = (const float*)d_in[15];
  const float* ln2s = (const float*)d_in[16];
  const float* ln2b = (const float*)d_in[17];
  const float* ln3s = (const float*)d_in[18];
  const float* ln3b = (const float*)d_in[19];
  const float* ff1w = (const float*)d_in[20];
  const float* ff1b = (const float*)d_in[21];
  const float* ff2w = (const float*)d_in[22];
  const float* ff2b = (const float*)d_in[23];
  const float* fcw = (const float*)d_in[24];
  const float* fcb = (const float*)d_in[25];

  // workspace carve — TOTAL 65 MiB:
  // [0,16M)    x16 bf16 residual (16384 x 512)
  // [16M,64M)  qkv bf16 16384x1536 (attn in-place on q-slice; out-proj delta
  //            into dead k-slice). FF phase: hbuf 32M + fdel 16M.
  // [64M,65M)  fp32 smalls: memv(128K) | cav(128K) | cavec(768K)
  char* w8 = (char*)d_ws;
  ushort* x16 = (ushort*)w8;
  ushort* qkv = (ushort*)(w8 + (16u << 20));
  ushort* hbuf = qkv;
  ushort* fdel = (ushort*)(w8 + (48u << 20));
  float* memv = (float*)(w8 + (64u << 20));
  float* cav = memv + 64 * 512;
  float* cavec = cav + 64 * 512;

  embed_kernel<<<16384, 256, 0, stream>>>(tgt, emb, pos, x16);

  // mem = z @ proj_w^T + proj_b (64x512, K=LAT=512), all fp32
  small_gemm<<<128, 256, 0, stream>>>(z, projw, projb, memv);
  // cross-attn collapses (kv len 1): cavec[l][b] = (mem Wv^T + bv) Wo^T + bo
  for (int i = 0; i < L_; ++i) {
    small_gemm<<<128, 256, 0, stream>>>(
        memv, caw + ((size_t)i * 1536 + 1024) * 512, cab + i * 1536 + 1024, cav);
    small_gemm<<<128, 256, 0, stream>>>(cav, caow + (size_t)i * 512 * 512,
                                        caob + i * 512, cavec + (size_t)i * 64 * 512);
  }

  for (int i = 0; i < L_; ++i) {
    // QKV: qkv(16384x1536) = x16 . sa_w^T + sa_b
    gemm_bt<0><<<dim3(12, 128), 256, 0, stream>>>(
        x16, saw + (size_t)i * 1536 * 512, sab + i * 1536, qkv, 1536, 512, 512,
        512, 1536);
    attn_kernel<<<dim3(H_, B_), 256, 0, stream>>>(qkv);
    // out-proj: k-slice(delta) = attn(q-slice, As=1536) . sa_ow^T + sa_ob
    gemm_bt<0><<<dim3(4, 128), 256, 0, stream>>>(
        qkv, saow + (size_t)i * 512 * 512, saob + i * 512, qkv + 512, 512, 512,
        1536, 512, 1536);
    ln_kernel<0><<<16384, 256, 0, stream>>>(x16, qkv + 512, 768, ln1s + i * 512,
                                            ln1b + i * 512);
    // cross-attn add (per-batch broadcast fp32) + LN2
    ln_kernel<1><<<16384, 256, 0, stream>>>(x16, cavec + (size_t)i * 64 * 512,
                                            256, ln2s + i * 512, ln2b + i * 512);
    // FFN split into two DFF=1024 chunks: hbuf 32M, fdel accumulates.
    gemm_bt<1><<<dim3(8, 128), 256, 0, stream>>>(
        x16, ff1w + (size_t)i * 2048 * 512, ff1b + i * 2048, hbuf, 1024, 512,
        512, 512, 1024);
    gemm_bt<0><<<dim3(4, 128), 256, 0, stream>>>(
        hbuf, ff2w + (size_t)i * 512 * 2048, ff2b + i * 512, fdel, 512, 1024,
        1024, 2048, 512);
    gemm_bt<1><<<dim3(8, 128), 256, 0, stream>>>(
        x16, ff1w + ((size_t)i * 2048 + 1024) * 512, ff1b + i * 2048 + 1024,
        hbuf, 1024, 512, 512, 512, 1024);
    gemm_bt<2><<<dim3(4, 128), 256, 0, stream>>>(
        hbuf, ff2w + (size_t)i * 512 * 2048 + 1024, (const float*)0, fdel, 512,
        1024, 1024, 2048, 512);
    ln_kernel<0><<<16384, 256, 0, stream>>>(x16, fdel, 256, ln3s + i * 512,
                                            ln3b + i * 512);
  }
  // logits -> d_out (fp32, 16384x128)
  gemm_bt<3><<<dim3(1, 128), 256, 0, stream>>>(x16, fcw, fcb, d_out, 128, 512,
                                               512, 512, 128);
}

// Round 5
// 2449.982 us; speedup vs baseline: 1.5106x; 1.5106x over previous
//
#include <hip/hip_runtime.h>

typedef unsigned int uint;
typedef unsigned short ushort;

typedef __attribute__((ext_vector_type(8))) __bf16 bf16x8;
typedef __attribute__((ext_vector_type(4))) float f32x4;

#define B_ 64
#define S_ 256
#define D_ 512
#define H_ 8
#define DFF_ 2048
#define V_ 128
#define L_ 6
#define BS_ (B_ * S_)

__device__ __forceinline__ float blo(uint u) { return __uint_as_float(u << 16); }
__device__ __forceinline__ float bhi(uint u) { return __uint_as_float(u & 0xffff0000u); }
__device__ __forceinline__ float b2f(ushort u) { return __uint_as_float(((uint)u) << 16); }
__device__ __forceinline__ ushort f2b(float f) {
  uint u = __float_as_uint(f);
  return (ushort)((u + 0x7fffu + ((u >> 16) & 1u)) >> 16);  // RTNE
}
__device__ __forceinline__ uint pack2(float a, float b) {
  return (uint)f2b(a) | ((uint)f2b(b) << 16);
}

#define GLOAD16(gp, lp)                                                        \
  __builtin_amdgcn_global_load_lds(                                            \
      (const __attribute__((address_space(1))) void*)(gp),                     \
      (__attribute__((address_space(3))) void*)(lp), 16, 0, 0)

// -------- fp32 -> bf16 bulk conversion (one-time per launch) ---------------
__global__ __launch_bounds__(256) void conv_kernel(const float* __restrict__ src,
                                                   ushort* __restrict__ dst) {
  size_t p = (size_t)blockIdx.x * 256 + threadIdx.x;
  float2 v = ((const float2*)src)[p];
  ((uint*)dst)[p] = pack2(v.x, v.y);
}

// -------- embedding: x16 = bf16(emb[tgt] + pos); emb/pos fp32 ---------------
__global__ __launch_bounds__(256) void embed_kernel(
    const int* __restrict__ tgt, const float* __restrict__ emb,
    const float* __restrict__ pos, ushort* __restrict__ x16) {
  int p = blockIdx.x * 256 + threadIdx.x;
  int row = p >> 8;
  int d2 = p & 255;
  int s = row & (S_ - 1);
  int tok = tgt[row];
  float2 e = ((const float2*)emb)[tok * 256 + d2];
  float2 pp = ((const float2*)pos)[s * 256 + d2];
  ((uint*)x16)[p] = pack2(e.x + pp.x, e.y + pp.y);
}

// ---- small fp32 GEMM: C[64][512] = A[64][512] . W[512][512]^T + bias ------
__global__ __launch_bounds__(256) void small_gemm(
    const float* __restrict__ A, const float* __restrict__ W,
    const float* __restrict__ bias, float* __restrict__ C) {
  int t = blockIdx.x * 256 + threadIdx.x;
  int m = t >> 9, n = t & 511;
  const float4* ap = (const float4*)(A + (size_t)m * 512);
  const float4* wp = (const float4*)(W + (size_t)n * 512);
  float acc = bias[n];
  for (int k4 = 0; k4 < 128; ++k4) {
    float4 a = ap[k4], w = wp[k4];
    acc += a.x * w.x + a.y * w.y + a.z * w.z + a.w * w.w;
  }
  C[t] = acc;
}

// --- MFMA GEMM (m97 structure): C = A[.,K](As) . W_bf16(Ws)[N][K]^T --------
// MODE 0: C=bf16(acc+bias)  1: relu  2: bf16 C+=acc (RMW)  3: fp32 C=acc+bias
// 128x128 tile, BK=32, global_load_lds width=16 staging.
// A-frag a[j]=A[m=tr][k=tq*8+j]; B-frag b[j]=W[n=tr][k=tq*8+j];
// C/D: reg r -> row=tq*4+r, col=tr  (conventions verified by round-4 pass).
template <int MODE>
__global__ __launch_bounds__(256) void gemm_bt(
    const ushort* __restrict__ A, const ushort* __restrict__ W,
    const float* __restrict__ bias, void* __restrict__ Cv, int N, int K,
    int As, int Ws, int Cs) {
  __shared__ ushort la[128 * 32];
  __shared__ ushort lb[128 * 32];
  const int tid = threadIdx.x;
  const int wv = tid >> 6, lane = tid & 63;
  const int m0 = blockIdx.y << 7, n0 = blockIdx.x << 7;
  const int wm = (wv >> 1) << 6, wn = (wv & 1) << 6;
  const int tr = lane & 15, tq = lane >> 4;

  const int lin0 = wv * 1024 + lane * 8;
  const int lin1 = lin0 + 512;
  const int am0 = lin0 >> 5, ac0 = lin0 & 31;
  const int am1 = lin1 >> 5, ac1 = lin1 & 31;

  const ushort* pa0 = A + (size_t)(m0 + am0) * As + ac0;
  const ushort* pa1 = A + (size_t)(m0 + am1) * As + ac1;
  const ushort* pb0 = W + (size_t)(n0 + am0) * Ws + ac0;
  const ushort* pb1 = W + (size_t)(n0 + am1) * Ws + ac1;
  ushort* la0 = &la[wv * 1024];
  ushort* la1 = &la[wv * 1024 + 512];
  ushort* lb0 = &lb[wv * 1024];
  ushort* lb1 = &lb[wv * 1024 + 512];

  f32x4 acc[4][4];
#pragma unroll
  for (int i = 0; i < 4; ++i)
#pragma unroll
    for (int j = 0; j < 4; ++j) acc[i][j] = (f32x4)(0.f);

  const int KT = K >> 5;
  for (int kt = 0; kt < KT; ++kt) {
    const int kb = kt << 5;
    GLOAD16(pa0 + kb, la0);
    GLOAD16(pa1 + kb, la1);
    GLOAD16(pb0 + kb, lb0);
    GLOAD16(pb1 + kb, lb1);
    __syncthreads();
    bf16x8 av[4], bv[4];
#pragma unroll
    for (int i = 0; i < 4; ++i)
      av[i] = *(const bf16x8*)&la[(wm + i * 16 + tr) * 32 + tq * 8];
#pragma unroll
    for (int j = 0; j < 4; ++j)
      bv[j] = *(const bf16x8*)&lb[(wn + j * 16 + tr) * 32 + tq * 8];
#pragma unroll
    for (int i = 0; i < 4; ++i)
#pragma unroll
      for (int j = 0; j < 4; ++j)
        acc[i][j] =
            __builtin_amdgcn_mfma_f32_16x16x32_bf16(av[i], bv[j], acc[i][j], 0, 0, 0);
    __syncthreads();
  }

#pragma unroll
  for (int j = 0; j < 4; ++j) {
    const int gn = n0 + wn + j * 16 + tr;
    float bj = 0.f;
    if (MODE != 2) bj = bias[gn];
#pragma unroll
    for (int i = 0; i < 4; ++i) {
      const int gmb = m0 + wm + i * 16 + tq * 4;
#pragma unroll
      for (int r = 0; r < 4; ++r) {
        const size_t idx = (size_t)(gmb + r) * Cs + gn;
        float v = acc[i][j][r] + bj;
        if (MODE == 1) v = fmaxf(v, 0.f);
        if (MODE == 3)
          ((float*)Cv)[idx] = v;
        else if (MODE == 2) {
          ushort* C = (ushort*)Cv;
          C[idx] = f2b(b2f(C[idx]) + acc[i][j][r]);
        } else
          ((ushort*)Cv)[idx] = f2b(v);
      }
    }
  }
}

// ---------------- MFMA causal attention ----------------
// grid (4 qchunks, H, B), block = 1 wave (64). Wave owns 64 q rows of (b,h),
// iterates key chunks 0..qc through LDS. In-place output over q-slice.
// No-max-sub softmax (scores O(1)); P relayed via LDS (C-layout -> A-layout).
__global__ __launch_bounds__(64) void attn_mfma(ushort* __restrict__ qkv) {
  __shared__ ushort lk[64 * 72];  // K chunk [key][64+pad]
  __shared__ ushort lv[64 * 72];  // V chunk [key][64+pad]
  __shared__ ushort lp[64 * 72];  // P       [qrow][64+pad]
  const int qc = blockIdx.x, h = blockIdx.y, b = blockIdx.z;
  const int lane = threadIdx.x, tr = lane & 15, tq = lane >> 4;
  const int q0 = qc << 6;
  const float SCL = 0.18033688011112042f;  // log2(e)/sqrt(64)

  // Q fragments (A-operand): qf[i][s][j] = Q[q0+i*16+tr][s*32+tq*8+j]
  bf16x8 qf[4][2];
#pragma unroll
  for (int i = 0; i < 4; ++i)
#pragma unroll
    for (int s = 0; s < 2; ++s)
      qf[i][s] = *(const bf16x8*)(qkv +
                                  (size_t)(b * 256 + q0 + i * 16 + tr) * 1536 +
                                  h * 64 + s * 32 + tq * 8);

  f32x4 o[4][4];
  float pl[4][4];
#pragma unroll
  for (int i = 0; i < 4; ++i)
#pragma unroll
    for (int j = 0; j < 4; ++j) {
      o[i][j] = (f32x4)(0.f);
      pl[i][j] = 0.f;
    }

  for (int c = 0; c <= qc; ++c) {
    // stage K,V chunk: thread=lane owns key row (c*64+lane)
    const ushort* gk =
        qkv + (size_t)(b * 256 + c * 64 + lane) * 1536 + 512 + h * 64;
#pragma unroll
    for (int jj = 0; jj < 8; ++jj) {
      *(uint4*)&lk[lane * 72 + jj * 8] = *(const uint4*)(gk + jj * 8);
      *(uint4*)&lv[lane * 72 + jj * 8] = *(const uint4*)(gk + 512 + jj * 8);
    }
    __syncthreads();

    // S = Q . K^T  (B-frag: kf[j][s][jj] = K[j*16+tr][s*32+tq*8+jj])
    f32x4 Sv[4][4];
#pragma unroll
    for (int i = 0; i < 4; ++i)
#pragma unroll
      for (int j = 0; j < 4; ++j) Sv[i][j] = (f32x4)(0.f);
    bf16x8 kf[4][2];
#pragma unroll
    for (int j = 0; j < 4; ++j)
#pragma unroll
      for (int s = 0; s < 2; ++s)
        kf[j][s] = *(const bf16x8*)&lk[(j * 16 + tr) * 72 + s * 32 + tq * 8];
#pragma unroll
    for (int i = 0; i < 4; ++i)
#pragma unroll
      for (int j = 0; j < 4; ++j) {
        Sv[i][j] = __builtin_amdgcn_mfma_f32_16x16x32_bf16(qf[i][0], kf[j][0],
                                                           Sv[i][j], 0, 0, 0);
        Sv[i][j] = __builtin_amdgcn_mfma_f32_16x16x32_bf16(qf[i][1], kf[j][1],
                                                           Sv[i][j], 0, 0, 0);
      }

    // exp2 + causal mask (diag chunk) + rowsum partials + P -> LDS (trunc)
    const bool diag = (c == qc);
#pragma unroll
    for (int i = 0; i < 4; ++i)
#pragma unroll
      for (int j = 0; j < 4; ++j)
#pragma unroll
        for (int r = 0; r < 4; ++r) {
          float e = exp2f(Sv[i][j][r] * SCL);
          if (diag && (j * 16 + tr) > (i * 16 + tq * 4 + r)) e = 0.f;
          pl[i][r] += e;
          lp[(i * 16 + tq * 4 + r) * 72 + j * 16 + tr] =
              (ushort)(__float_as_uint(e) >> 16);  // trunc: P in [0,1]
        }
    __syncthreads();

    // O += P . V  (A-frag from lp rows; B-frag gathered from lv columns)
#pragma unroll
    for (int s = 0; s < 2; ++s) {
      bf16x8 vf[4];
#pragma unroll
      for (int jn = 0; jn < 4; ++jn) {
        uint u0 = (uint)lv[(s * 32 + tq * 8 + 0) * 72 + jn * 16 + tr] |
                  ((uint)lv[(s * 32 + tq * 8 + 1) * 72 + jn * 16 + tr] << 16);
        uint u1 = (uint)lv[(s * 32 + tq * 8 + 2) * 72 + jn * 16 + tr] |
                  ((uint)lv[(s * 32 + tq * 8 + 3) * 72 + jn * 16 + tr] << 16);
        uint u2 = (uint)lv[(s * 32 + tq * 8 + 4) * 72 + jn * 16 + tr] |
                  ((uint)lv[(s * 32 + tq * 8 + 5) * 72 + jn * 16 + tr] << 16);
        uint u3 = (uint)lv[(s * 32 + tq * 8 + 6) * 72 + jn * 16 + tr] |
                  ((uint)lv[(s * 32 + tq * 8 + 7) * 72 + jn * 16 + tr] << 16);
        vf[jn] = __builtin_bit_cast(bf16x8, make_uint4(u0, u1, u2, u3));
      }
      bf16x8 af[4];
#pragma unroll
      for (int im = 0; im < 4; ++im)
        af[im] = *(const bf16x8*)&lp[(im * 16 + tr) * 72 + s * 32 + tq * 8];
#pragma unroll
      for (int im = 0; im < 4; ++im)
#pragma unroll
        for (int jn = 0; jn < 4; ++jn)
          o[im][jn] = __builtin_amdgcn_mfma_f32_16x16x32_bf16(af[im], vf[jn],
                                                              o[im][jn], 0, 0, 0);
    }
    __syncthreads();  // protect lk/lv/lp reuse next chunk
  }

  // full rowsums: reduce pl over the 16 tr-lanes of this tq group
#pragma unroll
  for (int i = 0; i < 4; ++i)
#pragma unroll
    for (int r = 0; r < 4; ++r) {
      float v = pl[i][r];
      v += __shfl_xor(v, 1, 64);
      v += __shfl_xor(v, 2, 64);
      v += __shfl_xor(v, 4, 64);
      v += __shfl_xor(v, 8, 64);
      pl[i][r] = 1.f / v;
    }

  // store O over q-slice (C-layout: row=q0+i*16+tq*4+r, col=j*16+tr)
#pragma unroll
  for (int i = 0; i < 4; ++i)
#pragma unroll
    for (int j = 0; j < 4; ++j)
#pragma unroll
      for (int r = 0; r < 4; ++r)
        qkv[(size_t)(b * 256 + q0 + i * 16 + tq * 4 + r) * 1536 + h * 64 +
            j * 16 + tr] = f2b(o[i][j][r] * pl[i][r]);
}

// -------- LayerNorm: x16 = bf16(LN(x16 + delta) * sc + bi), in place --------
template <int DM>
__global__ __launch_bounds__(256) void ln_kernel(
    ushort* __restrict__ x16, const void* __restrict__ delta, int DsU,
    const float* __restrict__ sc, const float* __restrict__ bi) {
  const int r = blockIdx.x, t = threadIdx.x;
  const int lane = t & 63, wv = t >> 6;
  uint* xr = (uint*)x16 + (size_t)r * 256;
  uint xu = xr[t];
  float d0, d1;
  if (DM == 0) {
    uint du = ((const uint*)delta)[(size_t)r * DsU + t];
    d0 = blo(du);
    d1 = bhi(du);
  } else {
    float2 dv = ((const float2*)delta)[(size_t)(r >> 8) * 256 + t];
    d0 = dv.x;
    d1 = dv.y;
  }
  float v0 = blo(xu) + d0, v1 = bhi(xu) + d1;
  float sm = v0 + v1, sq = v0 * v0 + v1 * v1;
#pragma unroll
  for (int o = 32; o > 0; o >>= 1) {
    sm += __shfl_xor(sm, o, 64);
    sq += __shfl_xor(sq, o, 64);
  }
  __shared__ float red[4][2];
  if (lane == 0) {
    red[wv][0] = sm;
    red[wv][1] = sq;
  }
  __syncthreads();
  sm = red[0][0] + red[1][0] + red[2][0] + red[3][0];
  sq = red[0][1] + red[1][1] + red[2][1] + red[3][1];
  float mean = sm * (1.f / 512.f);
  float var = sq * (1.f / 512.f) - mean * mean;
  float rs = rsqrtf(var + 1e-5f);
  float2 s2 = ((const float2*)sc)[t];
  float2 b2 = ((const float2*)bi)[t];
  float y0 = (v0 - mean) * rs * s2.x + b2.x;
  float y1 = (v1 - mean) * rs * s2.y + b2.y;
  xr[t] = pack2(y0, y1);
}

extern "C" void kernel_launch(void* const* d_in, const int* in_sizes, int n_in,
                              void* d_out, int out_size, void* d_ws,
                              size_t ws_size, hipStream_t stream) {
  (void)in_sizes; (void)n_in; (void)out_size; (void)ws_size;
  const float* z = (const float*)d_in[0];
  const int* tgt = (const int*)d_in[1];
  const float* emb = (const float*)d_in[2];
  const float* pos = (const float*)d_in[3];
  const float* projw = (const float*)d_in[4];
  const float* projb = (const float*)d_in[5];
  const float* saw = (const float*)d_in[6];
  const float* sab = (const float*)d_in[7];
  const float* saow = (const float*)d_in[8];
  const float* saob = (const float*)d_in[9];
  const float* caw = (const float*)d_in[10];
  const float* cab = (const float*)d_in[11];
  const float* caow = (const float*)d_in[12];
  const float* caob = (const float*)d_in[13];
  const float* ln1s = (const float*)d_in[14];
  const float* ln1b = (const float*)d_in[15];
  const float* ln2s = (const float*)d_in[16];
  const float* ln2b = (const float*)d_in[17];
  const float* ln3s = (const float*)d_in[18];
  const float* ln3b = (const float*)d_in[19];
  const float* ff1w = (const float*)d_in[20];
  const float* ff1b = (const float*)d_in[21];
  const float* ff2w = (const float*)d_in[22];
  const float* ff2b = (const float*)d_in[23];
  const float* fcw = (const float*)d_in[24];
  const float* fcb = (const float*)d_in[25];

  // workspace carve — TOTAL ~102 MiB:
  // [0,16M)    x16 bf16 residual
  // [16M,64M)  qkv 48M (attn in-place; out-proj delta in dead k-slice);
  //            FF phase: hbuf 32M + fdel 16M
  // [64M,65M)  fp32 smalls
  // [65M,~102M) bf16 weights (converted once per launch)
  char* w8 = (char*)d_ws;
  ushort* x16 = (ushort*)w8;
  ushort* qkv = (ushort*)(w8 + (16u << 20));
  ushort* hbuf = qkv;
  ushort* fdel = (ushort*)(w8 + (48u << 20));
  float* memv = (float*)(w8 + (64u << 20));
  float* cav = memv + 64 * 512;
  float* cavec = cav + 64 * 512;
  ushort* wsaw = (ushort*)(w8 + (65u << 20));       // 6*1536*512
  ushort* wsaow = wsaw + (size_t)L_ * 1536 * 512;   // 6*512*512
  ushort* wff1 = wsaow + (size_t)L_ * 512 * 512;    // 6*2048*512
  ushort* wff2 = wff1 + (size_t)L_ * 2048 * 512;    // 6*512*2048
  ushort* wfcw = wff2 + (size_t)L_ * 512 * 2048;    // 128*512

  // one-time weight conversions (fp32 -> bf16)
  conv_kernel<<<(L_ * 1536 * 512) / 512, 256, 0, stream>>>(saw, wsaw);
  conv_kernel<<<(L_ * 512 * 512) / 512, 256, 0, stream>>>(saow, wsaow);
  conv_kernel<<<(L_ * 2048 * 512) / 512, 256, 0, stream>>>(ff1w, wff1);
  conv_kernel<<<(L_ * 512 * 2048) / 512, 256, 0, stream>>>(ff2w, wff2);
  conv_kernel<<<(V_ * 512) / 512, 256, 0, stream>>>(fcw, wfcw);

  embed_kernel<<<16384, 256, 0, stream>>>(tgt, emb, pos, x16);

  small_gemm<<<128, 256, 0, stream>>>(z, projw, projb, memv);
  for (int i = 0; i < L_; ++i) {
    small_gemm<<<128, 256, 0, stream>>>(
        memv, caw + ((size_t)i * 1536 + 1024) * 512, cab + i * 1536 + 1024, cav);
    small_gemm<<<128, 256, 0, stream>>>(cav, caow + (size_t)i * 512 * 512,
                                        caob + i * 512, cavec + (size_t)i * 64 * 512);
  }

  for (int i = 0; i < L_; ++i) {
    gemm_bt<0><<<dim3(12, 128), 256, 0, stream>>>(
        x16, wsaw + (size_t)i * 1536 * 512, sab + i * 1536, qkv, 1536, 512, 512,
        512, 1536);
    attn_mfma<<<dim3(4, H_, B_), 64, 0, stream>>>(qkv);
    gemm_bt<0><<<dim3(4, 128), 256, 0, stream>>>(
        qkv, wsaow + (size_t)i * 512 * 512, saob + i * 512, qkv + 512, 512, 512,
        1536, 512, 1536);
    ln_kernel<0><<<16384, 256, 0, stream>>>(x16, qkv + 512, 768, ln1s + i * 512,
                                            ln1b + i * 512);
    ln_kernel<1><<<16384, 256, 0, stream>>>(x16, cavec + (size_t)i * 64 * 512,
                                            256, ln2s + i * 512, ln2b + i * 512);
    gemm_bt<1><<<dim3(8, 128), 256, 0, stream>>>(
        x16, wff1 + (size_t)i * 2048 * 512, ff1b + i * 2048, hbuf, 1024, 512,
        512, 512, 1024);
    gemm_bt<0><<<dim3(4, 128), 256, 0, stream>>>(
        hbuf, wff2 + (size_t)i * 512 * 2048, ff2b + i * 512, fdel, 512, 1024,
        1024, 2048, 512);
    gemm_bt<1><<<dim3(8, 128), 256, 0, stream>>>(
        x16, wff1 + ((size_t)i * 2048 + 1024) * 512, ff1b + i * 2048 + 1024,
        hbuf, 1024, 512, 512, 512, 1024);
    gemm_bt<2><<<dim3(4, 128), 256, 0, stream>>>(
        hbuf, wff2 + (size_t)i * 512 * 2048 + 1024, (const float*)0, fdel, 512,
        1024, 1024, 2048, 512);
    ln_kernel<0><<<16384, 256, 0, stream>>>(x16, fdel, 256, ln3s + i * 512,
                                            ln3b + i * 512);
  }
  gemm_bt<3><<<dim3(1, 128), 256, 0, stream>>>(x16, wfcw, fcb, d_out, 128, 512,
                                               512, 512, 128);
}

// Round 6
// 1980.624 us; speedup vs baseline: 1.8685x; 1.2370x over previous
//
#include <hip/hip_runtime.h>

typedef unsigned int uint;
typedef unsigned short ushort;

typedef __attribute__((ext_vector_type(8))) __bf16 bf16x8;
typedef __attribute__((ext_vector_type(4))) float f32x4;

#define B_ 64
#define S_ 256
#define D_ 512
#define H_ 8
#define DFF_ 2048
#define V_ 128
#define L_ 6
#define BS_ (B_ * S_)

__device__ __forceinline__ float blo(uint u) { return __uint_as_float(u << 16); }
__device__ __forceinline__ float bhi(uint u) { return __uint_as_float(u & 0xffff0000u); }
__device__ __forceinline__ float b2f(ushort u) { return __uint_as_float(((uint)u) << 16); }
__device__ __forceinline__ ushort f2b(float f) {
  uint u = __float_as_uint(f);
  return (ushort)((u + 0x7fffu + ((u >> 16) & 1u)) >> 16);  // RTNE
}
__device__ __forceinline__ uint pack2(float a, float b) {
  return (uint)f2b(a) | ((uint)f2b(b) << 16);
}

#define GLOAD16(gp, lp)                                                        \
  __builtin_amdgcn_global_load_lds(                                            \
      (const __attribute__((address_space(1))) void*)(gp),                     \
      (__attribute__((address_space(3))) void*)(lp), 16, 0, 0)

// -------- fp32 -> bf16 bulk conversion (one-time per launch) ---------------
__global__ __launch_bounds__(256) void conv_kernel(const float* __restrict__ src,
                                                   ushort* __restrict__ dst) {
  size_t p = (size_t)blockIdx.x * 256 + threadIdx.x;
  float2 v = ((const float2*)src)[p];
  ((uint*)dst)[p] = pack2(v.x, v.y);
}

// -------- embedding: x16 = bf16(emb[tgt] + pos); emb/pos fp32 ---------------
__global__ __launch_bounds__(256) void embed_kernel(
    const int* __restrict__ tgt, const float* __restrict__ emb,
    const float* __restrict__ pos, ushort* __restrict__ x16) {
  int p = blockIdx.x * 256 + threadIdx.x;
  int row = p >> 8;
  int d2 = p & 255;
  int s = row & (S_ - 1);
  int tok = tgt[row];
  float2 e = ((const float2*)emb)[tok * 256 + d2];
  float2 pp = ((const float2*)pos)[s * 256 + d2];
  ((uint*)x16)[p] = pack2(e.x + pp.x, e.y + pp.y);
}

// ---- small fp32 GEMM: C[64][512] = A[64][512] . W[512][512]^T + bias ------
__global__ __launch_bounds__(256) void small_gemm(
    const float* __restrict__ A, const float* __restrict__ W,
    const float* __restrict__ bias, float* __restrict__ C) {
  int t = blockIdx.x * 256 + threadIdx.x;
  int m = t >> 9, n = t & 511;
  const float4* ap = (const float4*)(A + (size_t)m * 512);
  const float4* wp = (const float4*)(W + (size_t)n * 512);
  float acc = bias[n];
  for (int k4 = 0; k4 < 128; ++k4) {
    float4 a = ap[k4], w = wp[k4];
    acc += a.x * w.x + a.y * w.y + a.z * w.z + a.w * w.w;
  }
  C[t] = acc;
}

// ---- batched small GEMM over L layers (blockIdx.y = layer) ----------------
__global__ __launch_bounds__(256) void small_gemm_b(
    const float* __restrict__ A, long Astr, const float* __restrict__ W,
    long Wstr, const float* __restrict__ bias, int bstr, float* __restrict__ C) {
  const int i = blockIdx.y;
  int t = blockIdx.x * 256 + threadIdx.x;
  int m = t >> 9, n = t & 511;
  const float4* ap = (const float4*)(A + Astr * i + (size_t)m * 512);
  const float4* wp = (const float4*)(W + Wstr * i + (size_t)n * 512);
  float acc = bias[(size_t)bstr * i + n];
  for (int k4 = 0; k4 < 128; ++k4) {
    float4 a = ap[k4], w = wp[k4];
    acc += a.x * w.x + a.y * w.y + a.z * w.z + a.w * w.w;
  }
  C[(size_t)i * 64 * 512 + t] = acc;
}

// --- MFMA GEMM (m97 structure): C = A[.,K](As) . W_bf16(Ws)[N][K]^T --------
// MODE 0: bf16(acc+bias)  1: relu  2: bf16 C+=acc  3: fp32 acc+bias
// MODE 4: bf16(acc+bias), cols<512 scaled by log2(e)/8 (Q pre-scale for attn)
template <int MODE>
__global__ __launch_bounds__(256) void gemm_bt(
    const ushort* __restrict__ A, const ushort* __restrict__ W,
    const float* __restrict__ bias, void* __restrict__ Cv, int N, int K,
    int As, int Ws, int Cs) {
  __shared__ ushort la[128 * 32];
  __shared__ ushort lb[128 * 32];
  const int tid = threadIdx.x;
  const int wv = tid >> 6, lane = tid & 63;
  const int m0 = blockIdx.y << 7, n0 = blockIdx.x << 7;
  const int wm = (wv >> 1) << 6, wn = (wv & 1) << 6;
  const int tr = lane & 15, tq = lane >> 4;

  const int lin0 = wv * 1024 + lane * 8;
  const int lin1 = lin0 + 512;
  const int am0 = lin0 >> 5, ac0 = lin0 & 31;
  const int am1 = lin1 >> 5, ac1 = lin1 & 31;

  const ushort* pa0 = A + (size_t)(m0 + am0) * As + ac0;
  const ushort* pa1 = A + (size_t)(m0 + am1) * As + ac1;
  const ushort* pb0 = W + (size_t)(n0 + am0) * Ws + ac0;
  const ushort* pb1 = W + (size_t)(n0 + am1) * Ws + ac1;
  ushort* la0 = &la[wv * 1024];
  ushort* la1 = &la[wv * 1024 + 512];
  ushort* lb0 = &lb[wv * 1024];
  ushort* lb1 = &lb[wv * 1024 + 512];

  f32x4 acc[4][4];
#pragma unroll
  for (int i = 0; i < 4; ++i)
#pragma unroll
    for (int j = 0; j < 4; ++j) acc[i][j] = (f32x4)(0.f);

  const int KT = K >> 5;
  for (int kt = 0; kt < KT; ++kt) {
    const int kb = kt << 5;
    GLOAD16(pa0 + kb, la0);
    GLOAD16(pa1 + kb, la1);
    GLOAD16(pb0 + kb, lb0);
    GLOAD16(pb1 + kb, lb1);
    __syncthreads();
    bf16x8 av[4], bv[4];
#pragma unroll
    for (int i = 0; i < 4; ++i)
      av[i] = *(const bf16x8*)&la[(wm + i * 16 + tr) * 32 + tq * 8];
#pragma unroll
    for (int j = 0; j < 4; ++j)
      bv[j] = *(const bf16x8*)&lb[(wn + j * 16 + tr) * 32 + tq * 8];
#pragma unroll
    for (int i = 0; i < 4; ++i)
#pragma unroll
      for (int j = 0; j < 4; ++j)
        acc[i][j] =
            __builtin_amdgcn_mfma_f32_16x16x32_bf16(av[i], bv[j], acc[i][j], 0, 0, 0);
    __syncthreads();
  }

#pragma unroll
  for (int j = 0; j < 4; ++j) {
    const int gn = n0 + wn + j * 16 + tr;
    float bj = 0.f;
    if (MODE != 2) bj = bias[gn];
    float scl = 1.f;
    if (MODE == 4) scl = (gn < 512) ? 0.18033688011112042f : 1.f;
#pragma unroll
    for (int i = 0; i < 4; ++i) {
      const int gmb = m0 + wm + i * 16 + tq * 4;
#pragma unroll
      for (int r = 0; r < 4; ++r) {
        const size_t idx = (size_t)(gmb + r) * Cs + gn;
        float v = acc[i][j][r] + bj;
        if (MODE == 1) v = fmaxf(v, 0.f);
        if (MODE == 4) v *= scl;
        if (MODE == 3)
          ((float*)Cv)[idx] = v;
        else if (MODE == 2) {
          ushort* C = (ushort*)Cv;
          C[idx] = f2b(b2f(C[idx]) + acc[i][j][r]);
        } else
          ((ushort*)Cv)[idx] = f2b(v);
      }
    }
  }
}

// ---------------- MFMA causal attention v2 ----------------
// grid (2, H, B), 128 threads (2 waves). Wave g owns q-chunk qc=2*qp+g.
// K staged [key][d]; V staged TRANSPOSED [d][key] so PV B-frags are b128.
// Q pre-scaled by log2(e)/8 in QKV GEMM. In-place output over q-slice.
__global__ __launch_bounds__(128) void attn_mfma(ushort* __restrict__ qkv) {
  __shared__ ushort lk[64 * 72];        // K chunk  [key][64+8]
  __shared__ ushort lvT[64 * 72];       // V^T      [d][64+8]
  __shared__ ushort lp[2 * 64 * 72];    // per-wave P [qrow][64+8]
  const int qp = blockIdx.x, h = blockIdx.y, b = blockIdx.z;
  const int tid = threadIdx.x;
  const int g = tid >> 6, lane = tid & 63;
  const int tr = lane & 15, tq = lane >> 4;
  const int qc = qp * 2 + g;
  const int q0 = qc << 6;
  ushort* myp = &lp[g * 64 * 72];

  // Q fragments (A-operand): qf[i][s][j] = Q[q0+i*16+tr][s*32+tq*8+j]
  bf16x8 qf[4][2];
#pragma unroll
  for (int i = 0; i < 4; ++i)
#pragma unroll
    for (int s = 0; s < 2; ++s)
      qf[i][s] = *(const bf16x8*)(qkv +
                                  (size_t)(b * 256 + q0 + i * 16 + tr) * 1536 +
                                  h * 64 + s * 32 + tq * 8);

  f32x4 o[4][4];
  float pl[4][4];
#pragma unroll
  for (int i = 0; i < 4; ++i)
#pragma unroll
    for (int j = 0; j < 4; ++j) {
      o[i][j] = (f32x4)(0.f);
      pl[i][j] = 0.f;
    }

  const int key = tid >> 1, half = tid & 1;
  const int cmax = qp * 2 + 1;
  for (int c = 0; c <= cmax; ++c) {
    __syncthreads();  // protect prior chunk's LDS reads (lk/lvT/lp)
    // cooperative staging: 2 threads per key row
    const ushort* gk =
        qkv + (size_t)(b * 256 + c * 64 + key) * 1536 + 512 + h * 64 + half * 32;
#pragma unroll
    for (int u = 0; u < 4; ++u)
      *(uint4*)&lk[key * 72 + half * 32 + u * 8] = *(const uint4*)(gk + u * 8);
    ushort vloc[32];
#pragma unroll
    for (int u = 0; u < 4; ++u)
      *(uint4*)&vloc[u * 8] = *(const uint4*)(gk + 512 + u * 8);
#pragma unroll
    for (int dd = 0; dd < 32; ++dd)
      lvT[(half * 32 + dd) * 72 + key] = vloc[dd];
    __syncthreads();

    const bool active = (c <= qc);
    if (active) {
      // S = Q . K^T
      f32x4 Sv[4][4];
#pragma unroll
      for (int i = 0; i < 4; ++i)
#pragma unroll
        for (int j = 0; j < 4; ++j) Sv[i][j] = (f32x4)(0.f);
      bf16x8 kf[4][2];
#pragma unroll
      for (int j = 0; j < 4; ++j)
#pragma unroll
        for (int s = 0; s < 2; ++s)
          kf[j][s] = *(const bf16x8*)&lk[(j * 16 + tr) * 72 + s * 32 + tq * 8];
#pragma unroll
      for (int i = 0; i < 4; ++i)
#pragma unroll
        for (int j = 0; j < 4; ++j) {
          Sv[i][j] = __builtin_amdgcn_mfma_f32_16x16x32_bf16(qf[i][0], kf[j][0],
                                                             Sv[i][j], 0, 0, 0);
          Sv[i][j] = __builtin_amdgcn_mfma_f32_16x16x32_bf16(qf[i][1], kf[j][1],
                                                             Sv[i][j], 0, 0, 0);
        }
      // exp2 (Q pre-scaled) + causal mask on diag chunk + partial rowsums
      const bool diag = (c == qc);
#pragma unroll
      for (int i = 0; i < 4; ++i)
#pragma unroll
        for (int j = 0; j < 4; ++j)
#pragma unroll
          for (int r = 0; r < 4; ++r) {
            float e = exp2f(Sv[i][j][r]);
            if (diag && (j * 16 + tr) > (i * 16 + tq * 4 + r)) e = 0.f;
            pl[i][r] += e;
            myp[(i * 16 + tq * 4 + r) * 72 + j * 16 + tr] =
                (ushort)(__float_as_uint(e) >> 16);  // trunc: P in [0,1]
          }
    }
    __syncthreads();  // make P visible for the relay read
    if (active) {
      // O += P . V   (both operands now contiguous b128 reads)
#pragma unroll
      for (int s = 0; s < 2; ++s) {
        bf16x8 vf[4], af[4];
#pragma unroll
        for (int jn = 0; jn < 4; ++jn)
          vf[jn] = *(const bf16x8*)&lvT[(jn * 16 + tr) * 72 + s * 32 + tq * 8];
#pragma unroll
        for (int im = 0; im < 4; ++im)
          af[im] = *(const bf16x8*)&myp[(im * 16 + tr) * 72 + s * 32 + tq * 8];
#pragma unroll
        for (int im = 0; im < 4; ++im)
#pragma unroll
          for (int jn = 0; jn < 4; ++jn)
            o[im][jn] = __builtin_amdgcn_mfma_f32_16x16x32_bf16(af[im], vf[jn],
                                                                o[im][jn], 0, 0, 0);
      }
    }
  }

  // full rowsums: reduce pl over the 16 tr-lanes of this tq group
#pragma unroll
  for (int i = 0; i < 4; ++i)
#pragma unroll
    for (int r = 0; r < 4; ++r) {
      float v = pl[i][r];
      v += __shfl_xor(v, 1, 64);
      v += __shfl_xor(v, 2, 64);
      v += __shfl_xor(v, 4, 64);
      v += __shfl_xor(v, 8, 64);
      pl[i][r] = 1.f / v;
    }

  // store O over q-slice (C-layout: row=q0+i*16+tq*4+r, col=j*16+tr)
#pragma unroll
  for (int i = 0; i < 4; ++i)
#pragma unroll
    for (int j = 0; j < 4; ++j)
#pragma unroll
      for (int r = 0; r < 4; ++r)
        qkv[(size_t)(b * 256 + q0 + i * 16 + tq * 4 + r) * 1536 + h * 64 +
            j * 16 + tr] = f2b(o[i][j][r] * pl[i][r]);
}

// ---- fused LN1+LN2: x = LN2(LN1(x + d1) + cavec[b]) -----------------------
__global__ __launch_bounds__(256) void ln12_kernel(
    ushort* __restrict__ x16, const uint* __restrict__ d1,
    const float2* __restrict__ cavec, const float* __restrict__ s1,
    const float* __restrict__ b1, const float* __restrict__ s2,
    const float* __restrict__ b2p) {
  const int r = blockIdx.x, t = threadIdx.x;
  const int lane = t & 63, wv = t >> 6;
  uint* xr = (uint*)x16 + (size_t)r * 256;
  uint xu = xr[t];
  uint du = d1[(size_t)r * 768 + t];
  float v0 = blo(xu) + blo(du), v1 = bhi(xu) + bhi(du);
  __shared__ float redA[4][2], redB[4][2];
  // --- LN1 ---
  float sm = v0 + v1, sq = v0 * v0 + v1 * v1;
#pragma unroll
  for (int o = 32; o > 0; o >>= 1) {
    sm += __shfl_xor(sm, o, 64);
    sq += __shfl_xor(sq, o, 64);
  }
  if (lane == 0) {
    redA[wv][0] = sm;
    redA[wv][1] = sq;
  }
  __syncthreads();
  sm = redA[0][0] + redA[1][0] + redA[2][0] + redA[3][0];
  sq = redA[0][1] + redA[1][1] + redA[2][1] + redA[3][1];
  float mean = sm * (1.f / 512.f);
  float var = sq * (1.f / 512.f) - mean * mean;
  float rs = rsqrtf(var + 1e-5f);
  float2 sa = ((const float2*)s1)[t];
  float2 ba = ((const float2*)b1)[t];
  float2 ca = cavec[(size_t)(r >> 8) * 256 + t];
  float w0 = (v0 - mean) * rs * sa.x + ba.x + ca.x;
  float w1 = (v1 - mean) * rs * sa.y + ba.y + ca.y;
  // --- LN2 ---
  sm = w0 + w1;
  sq = w0 * w0 + w1 * w1;
#pragma unroll
  for (int o = 32; o > 0; o >>= 1) {
    sm += __shfl_xor(sm, o, 64);
    sq += __shfl_xor(sq, o, 64);
  }
  if (lane == 0) {
    redB[wv][0] = sm;
    redB[wv][1] = sq;
  }
  __syncthreads();
  sm = redB[0][0] + redB[1][0] + redB[2][0] + redB[3][0];
  sq = redB[0][1] + redB[1][1] + redB[2][1] + redB[3][1];
  mean = sm * (1.f / 512.f);
  var = sq * (1.f / 512.f) - mean * mean;
  rs = rsqrtf(var + 1e-5f);
  float2 sb = ((const float2*)s2)[t];
  float2 bb = ((const float2*)b2p)[t];
  float y0 = (w0 - mean) * rs * sb.x + bb.x;
  float y1 = (w1 - mean) * rs * sb.y + bb.y;
  xr[t] = pack2(y0, y1);
}

// -------- LayerNorm: x16 = bf16(LN(x16 + delta) * sc + bi), in place --------
__global__ __launch_bounds__(256) void ln_kernel(
    ushort* __restrict__ x16, const uint* __restrict__ delta, int DsU,
    const float* __restrict__ sc, const float* __restrict__ bi) {
  const int r = blockIdx.x, t = threadIdx.x;
  const int lane = t & 63, wv = t >> 6;
  uint* xr = (uint*)x16 + (size_t)r * 256;
  uint xu = xr[t];
  uint du = delta[(size_t)r * DsU + t];
  float v0 = blo(xu) + blo(du), v1 = bhi(xu) + bhi(du);
  float sm = v0 + v1, sq = v0 * v0 + v1 * v1;
#pragma unroll
  for (int o = 32; o > 0; o >>= 1) {
    sm += __shfl_xor(sm, o, 64);
    sq += __shfl_xor(sq, o, 64);
  }
  __shared__ float red[4][2];
  if (lane == 0) {
    red[wv][0] = sm;
    red[wv][1] = sq;
  }
  __syncthreads();
  sm = red[0][0] + red[1][0] + red[2][0] + red[3][0];
  sq = red[0][1] + red[1][1] + red[2][1] + red[3][1];
  float mean = sm * (1.f / 512.f);
  float var = sq * (1.f / 512.f) - mean * mean;
  float rs = rsqrtf(var + 1e-5f);
  float2 s2 = ((const float2*)sc)[t];
  float2 b2 = ((const float2*)bi)[t];
  float y0 = (v0 - mean) * rs * s2.x + b2.x;
  float y1 = (v1 - mean) * rs * s2.y + b2.y;
  xr[t] = pack2(y0, y1);
}

extern "C" void kernel_launch(void* const* d_in, const int* in_sizes, int n_in,
                              void* d_out, int out_size, void* d_ws,
                              size_t ws_size, hipStream_t stream) {
  (void)in_sizes; (void)n_in; (void)out_size; (void)ws_size;
  const float* z = (const float*)d_in[0];
  const int* tgt = (const int*)d_in[1];
  const float* emb = (const float*)d_in[2];
  const float* pos = (const float*)d_in[3];
  const float* projw = (const float*)d_in[4];
  const float* projb = (const float*)d_in[5];
  const float* saw = (const float*)d_in[6];
  const float* sab = (const float*)d_in[7];
  const float* saow = (const float*)d_in[8];
  const float* saob = (const float*)d_in[9];
  const float* caw = (const float*)d_in[10];
  const float* cab = (const float*)d_in[11];
  const float* caow = (const float*)d_in[12];
  const float* caob = (const float*)d_in[13];
  const float* ln1s = (const float*)d_in[14];
  const float* ln1b = (const float*)d_in[15];
  const float* ln2s = (const float*)d_in[16];
  const float* ln2b = (const float*)d_in[17];
  const float* ln3s = (const float*)d_in[18];
  const float* ln3b = (const float*)d_in[19];
  const float* ff1w = (const float*)d_in[20];
  const float* ff1b = (const float*)d_in[21];
  const float* ff2w = (const float*)d_in[22];
  const float* ff2b = (const float*)d_in[23];
  const float* fcw = (const float*)d_in[24];
  const float* fcb = (const float*)d_in[25];

  // workspace carve — TOTAL ~103 MiB:
  // [0,16M)    x16 bf16 residual
  // [16M,64M)  qkv 48M (attn in-place; out-proj delta in dead k-slice);
  //            FF phase: hbuf 32M + fdel 16M
  // [64M,66M)  fp32 smalls: memv 128K | cav_all 768K | cavec 768K
  // [66M,~103M) bf16 weights (converted once per launch)
  char* w8 = (char*)d_ws;
  ushort* x16 = (ushort*)w8;
  ushort* qkv = (ushort*)(w8 + (16u << 20));
  ushort* hbuf = qkv;
  ushort* fdel = (ushort*)(w8 + (48u << 20));
  float* memv = (float*)(w8 + (64u << 20));
  float* cav_all = memv + 64 * 512;                  // 6 * 64*512
  float* cavec = cav_all + (size_t)L_ * 64 * 512;    // 6 * 64*512
  ushort* wsaw = (ushort*)(w8 + (66u << 20));        // 6*1536*512
  ushort* wsaow = wsaw + (size_t)L_ * 1536 * 512;    // 6*512*512
  ushort* wff1 = wsaow + (size_t)L_ * 512 * 512;     // 6*2048*512
  ushort* wff2 = wff1 + (size_t)L_ * 2048 * 512;     // 6*512*2048
  ushort* wfcw = wff2 + (size_t)L_ * 512 * 2048;     // 128*512

  // one-time weight conversions (fp32 -> bf16)
  conv_kernel<<<(L_ * 1536 * 512) / 512, 256, 0, stream>>>(saw, wsaw);
  conv_kernel<<<(L_ * 512 * 512) / 512, 256, 0, stream>>>(saow, wsaow);
  conv_kernel<<<(L_ * 2048 * 512) / 512, 256, 0, stream>>>(ff1w, wff1);
  conv_kernel<<<(L_ * 512 * 2048) / 512, 256, 0, stream>>>(ff2w, wff2);
  conv_kernel<<<(V_ * 512) / 512, 256, 0, stream>>>(fcw, wfcw);

  embed_kernel<<<16384, 256, 0, stream>>>(tgt, emb, pos, x16);

  // collapsed cross-attention (kv len 1), batched over layers
  small_gemm<<<128, 256, 0, stream>>>(z, projw, projb, memv);
  small_gemm_b<<<dim3(128, L_), 256, 0, stream>>>(
      memv, 0, caw + 1024 * 512, (long)1536 * 512, cab + 1024, 1536, cav_all);
  small_gemm_b<<<dim3(128, L_), 256, 0, stream>>>(
      cav_all, 64 * 512, caow, (long)512 * 512, caob, 512, cavec);

  for (int i = 0; i < L_; ++i) {
    // QKV (+ Q pre-scale): qkv = x16 . sa_w^T + sa_b
    gemm_bt<4><<<dim3(12, 128), 256, 0, stream>>>(
        x16, wsaw + (size_t)i * 1536 * 512, sab + i * 1536, qkv, 1536, 512, 512,
        512, 1536);
    attn_mfma<<<dim3(2, H_, B_), 128, 0, stream>>>(qkv);
    // out-proj -> dead k-slice
    gemm_bt<0><<<dim3(4, 128), 256, 0, stream>>>(
        qkv, wsaow + (size_t)i * 512 * 512, saob + i * 512, qkv + 512, 512, 512,
        1536, 512, 1536);
    // fused LN1 + cross-attn add + LN2
    ln12_kernel<<<16384, 256, 0, stream>>>(
        x16, (const uint*)(qkv + 512), (const float2*)(cavec + (size_t)i * 64 * 512),
        ln1s + i * 512, ln1b + i * 512, ln2s + i * 512, ln2b + i * 512);
    // FFN split into two DFF=1024 chunks
    gemm_bt<1><<<dim3(8, 128), 256, 0, stream>>>(
        x16, wff1 + (size_t)i * 2048 * 512, ff1b + i * 2048, hbuf, 1024, 512,
        512, 512, 1024);
    gemm_bt<0><<<dim3(4, 128), 256, 0, stream>>>(
        hbuf, wff2 + (size_t)i * 512 * 2048, ff2b + i * 512, fdel, 512, 1024,
        1024, 2048, 512);
    gemm_bt<1><<<dim3(8, 128), 256, 0, stream>>>(
        x16, wff1 + ((size_t)i * 2048 + 1024) * 512, ff1b + i * 2048 + 1024,
        hbuf, 1024, 512, 512, 512, 1024);
    gemm_bt<2><<<dim3(4, 128), 256, 0, stream>>>(
        hbuf, wff2 + (size_t)i * 512 * 2048 + 1024, (const float*)0, fdel, 512,
        1024, 1024, 2048, 512);
    ln_kernel<<<16384, 256, 0, stream>>>(x16, (const uint*)fdel, 256,
                                         ln3s + i * 512, ln3b + i * 512);
  }
  gemm_bt<3><<<dim3(1, 128), 256, 0, stream>>>(x16, wfcw, fcb, d_out, 128, 512,
                                               512, 512, 128);
}

// Round 7
// 1917.384 us; speedup vs baseline: 1.9302x; 1.0330x over previous
//
#include <hip/hip_runtime.h>

typedef unsigned int uint;
typedef unsigned short ushort;

typedef __attribute__((ext_vector_type(8))) __bf16 bf16x8;
typedef __attribute__((ext_vector_type(4))) float f32x4;

#define B_ 64
#define S_ 256
#define D_ 512
#define H_ 8
#define DFF_ 2048
#define V_ 128
#define L_ 6
#define BS_ (B_ * S_)

__device__ __forceinline__ float blo(uint u) { return __uint_as_float(u << 16); }
__device__ __forceinline__ float bhi(uint u) { return __uint_as_float(u & 0xffff0000u); }
__device__ __forceinline__ float b2f(ushort u) { return __uint_as_float(((uint)u) << 16); }
__device__ __forceinline__ ushort f2b(float f) {
  uint u = __float_as_uint(f);
  return (ushort)((u + 0x7fffu + ((u >> 16) & 1u)) >> 16);  // RTNE
}
__device__ __forceinline__ uint pack2(float a, float b) {
  return (uint)f2b(a) | ((uint)f2b(b) << 16);
}

#define GLOAD16(gp, lp)                                                        \
  __builtin_amdgcn_global_load_lds(                                            \
      (const __attribute__((address_space(1))) void*)(gp),                     \
      (__attribute__((address_space(3))) void*)(lp), 16, 0, 0)

// -------- fp32 -> bf16 bulk conversion (one-time per launch) ---------------
__global__ __launch_bounds__(256) void conv_kernel(const float* __restrict__ src,
                                                   ushort* __restrict__ dst) {
  size_t p = (size_t)blockIdx.x * 256 + threadIdx.x;
  float2 v = ((const float2*)src)[p];
  ((uint*)dst)[p] = pack2(v.x, v.y);
}

// -------- embedding: x16 = bf16(emb[tgt] + pos); emb/pos fp32 ---------------
__global__ __launch_bounds__(256) void embed_kernel(
    const int* __restrict__ tgt, const float* __restrict__ emb,
    const float* __restrict__ pos, ushort* __restrict__ x16) {
  int p = blockIdx.x * 256 + threadIdx.x;
  int row = p >> 8;
  int d2 = p & 255;
  int s = row & (S_ - 1);
  int tok = tgt[row];
  float2 e = ((const float2*)emb)[tok * 256 + d2];
  float2 pp = ((const float2*)pos)[s * 256 + d2];
  ((uint*)x16)[p] = pack2(e.x + pp.x, e.y + pp.y);
}

// --- MFMA GEMM (m97 structure): C = A[.,K](As) . W_bf16(Ws)[N][K]^T --------
// MODE 0: bf16(acc+bias)  1: relu  2: bf16 C+=acc  3: fp32 acc+bias
// MODE 4: bf16(acc+bias), cols<512 scaled by log2(e)/8 (Q pre-scale for attn)
template <int MODE>
__global__ __launch_bounds__(256) void gemm_bt(
    const ushort* __restrict__ A, const ushort* __restrict__ W,
    const float* __restrict__ bias, void* __restrict__ Cv, int N, int K,
    int As, int Ws, int Cs) {
  __shared__ ushort la[128 * 32];
  __shared__ ushort lb[128 * 32];
  const int tid = threadIdx.x;
  const int wv = tid >> 6, lane = tid & 63;
  const int m0 = blockIdx.y << 7, n0 = blockIdx.x << 7;
  const int wm = (wv >> 1) << 6, wn = (wv & 1) << 6;
  const int tr = lane & 15, tq = lane >> 4;

  const int lin0 = wv * 1024 + lane * 8;
  const int lin1 = lin0 + 512;
  const int am0 = lin0 >> 5, ac0 = lin0 & 31;
  const int am1 = lin1 >> 5, ac1 = lin1 & 31;

  const ushort* pa0 = A + (size_t)(m0 + am0) * As + ac0;
  const ushort* pa1 = A + (size_t)(m0 + am1) * As + ac1;
  const ushort* pb0 = W + (size_t)(n0 + am0) * Ws + ac0;
  const ushort* pb1 = W + (size_t)(n0 + am1) * Ws + ac1;
  ushort* la0 = &la[wv * 1024];
  ushort* la1 = &la[wv * 1024 + 512];
  ushort* lb0 = &lb[wv * 1024];
  ushort* lb1 = &lb[wv * 1024 + 512];

  f32x4 acc[4][4];
#pragma unroll
  for (int i = 0; i < 4; ++i)
#pragma unroll
    for (int j = 0; j < 4; ++j) acc[i][j] = (f32x4)(0.f);

  const int KT = K >> 5;
  for (int kt = 0; kt < KT; ++kt) {
    const int kb = kt << 5;
    GLOAD16(pa0 + kb, la0);
    GLOAD16(pa1 + kb, la1);
    GLOAD16(pb0 + kb, lb0);
    GLOAD16(pb1 + kb, lb1);
    __syncthreads();
    bf16x8 av[4], bv[4];
#pragma unroll
    for (int i = 0; i < 4; ++i)
      av[i] = *(const bf16x8*)&la[(wm + i * 16 + tr) * 32 + tq * 8];
#pragma unroll
    for (int j = 0; j < 4; ++j)
      bv[j] = *(const bf16x8*)&lb[(wn + j * 16 + tr) * 32 + tq * 8];
#pragma unroll
    for (int i = 0; i < 4; ++i)
#pragma unroll
      for (int j = 0; j < 4; ++j)
        acc[i][j] =
            __builtin_amdgcn_mfma_f32_16x16x32_bf16(av[i], bv[j], acc[i][j], 0, 0, 0);
    __syncthreads();
  }

#pragma unroll
  for (int j = 0; j < 4; ++j) {
    const int gn = n0 + wn + j * 16 + tr;
    float bj = 0.f;
    if (MODE != 2) bj = bias[gn];
    float scl = 1.f;
    if (MODE == 4) scl = (gn < 512) ? 0.18033688011112042f : 1.f;
#pragma unroll
    for (int i = 0; i < 4; ++i) {
      const int gmb = m0 + wm + i * 16 + tq * 4;
#pragma unroll
      for (int r = 0; r < 4; ++r) {
        const size_t idx = (size_t)(gmb + r) * Cs + gn;
        float v = acc[i][j][r] + bj;
        if (MODE == 1) v = fmaxf(v, 0.f);
        if (MODE == 4) v *= scl;
        if (MODE == 3)
          ((float*)Cv)[idx] = v;
        else if (MODE == 2) {
          ushort* C = (ushort*)Cv;
          C[idx] = f2b(b2f(C[idx]) + acc[i][j][r]);
        } else
          ((ushort*)Cv)[idx] = f2b(v);
      }
    }
  }
}

// --- batched MFMA GEMM, W fp32 converted during staging (Round-4-verified) --
// C_z = A_z[.,K](As) . W_z(Ws)[N][K]^T + bias_z ; z = blockIdx.z
__global__ __launch_bounds__(256) void gemm_btf(
    const ushort* __restrict__ A0, long zA, const float* __restrict__ W0,
    long zW, const float* __restrict__ bias0, long zb, ushort* __restrict__ C0,
    long zC, int N, int K, int As, int Ws, int Cs) {
  const int zz = blockIdx.z;
  const ushort* A = A0 + zA * zz;
  const float* W = W0 + zW * zz;
  const float* bias = bias0 + zb * zz;
  ushort* C = C0 + zC * zz;

  __shared__ ushort la[128 * 32];
  __shared__ ushort lb[128 * 32];
  const int tid = threadIdx.x;
  const int wv = tid >> 6, lane = tid & 63;
  const int m0 = blockIdx.y << 7, n0 = blockIdx.x << 7;
  const int wm = (wv >> 1) << 6, wn = (wv & 1) << 6;
  const int tr = lane & 15, tq = lane >> 4;

  const int lin0 = wv * 1024 + lane * 8;
  const int lin1 = lin0 + 512;
  const int am0 = lin0 >> 5, ac0 = lin0 & 31;
  const int am1 = lin1 >> 5, ac1 = lin1 & 31;

  const ushort* pa0 = A + (size_t)(m0 + am0) * As + ac0;
  const ushort* pa1 = A + (size_t)(m0 + am1) * As + ac1;
  const float* pb0 = W + (size_t)(n0 + am0) * Ws + ac0;
  const float* pb1 = W + (size_t)(n0 + am1) * Ws + ac1;

  f32x4 acc[4][4];
#pragma unroll
  for (int i = 0; i < 4; ++i)
#pragma unroll
    for (int j = 0; j < 4; ++j) acc[i][j] = (f32x4)(0.f);

  const int KT = K >> 5;
  for (int kt = 0; kt < KT; ++kt) {
    const int kb = kt << 5;
    uint4 ra0 = *(const uint4*)(pa0 + kb);
    uint4 ra1 = *(const uint4*)(pa1 + kb);
    float4 f00 = *(const float4*)(pb0 + kb);
    float4 f01 = *(const float4*)(pb0 + kb + 4);
    float4 f10 = *(const float4*)(pb1 + kb);
    float4 f11 = *(const float4*)(pb1 + kb + 4);
    uint4 rb0 = make_uint4(pack2(f00.x, f00.y), pack2(f00.z, f00.w),
                           pack2(f01.x, f01.y), pack2(f01.z, f01.w));
    uint4 rb1 = make_uint4(pack2(f10.x, f10.y), pack2(f10.z, f10.w),
                           pack2(f11.x, f11.y), pack2(f11.z, f11.w));
    __syncthreads();
    *(uint4*)&la[lin0] = ra0;
    *(uint4*)&la[lin1] = ra1;
    *(uint4*)&lb[lin0] = rb0;
    *(uint4*)&lb[lin1] = rb1;
    __syncthreads();
    bf16x8 av[4], bv[4];
#pragma unroll
    for (int i = 0; i < 4; ++i)
      av[i] = *(const bf16x8*)&la[(wm + i * 16 + tr) * 32 + tq * 8];
#pragma unroll
    for (int j = 0; j < 4; ++j)
      bv[j] = *(const bf16x8*)&lb[(wn + j * 16 + tr) * 32 + tq * 8];
#pragma unroll
    for (int i = 0; i < 4; ++i)
#pragma unroll
      for (int j = 0; j < 4; ++j)
        acc[i][j] =
            __builtin_amdgcn_mfma_f32_16x16x32_bf16(av[i], bv[j], acc[i][j], 0, 0, 0);
  }

#pragma unroll
  for (int j = 0; j < 4; ++j) {
    const int gn = n0 + wn + j * 16 + tr;
    const float bj = bias[gn];
#pragma unroll
    for (int i = 0; i < 4; ++i) {
      const int gmb = m0 + wm + i * 16 + tq * 4;
#pragma unroll
      for (int r = 0; r < 4; ++r)
        C[(size_t)(gmb + r) * Cs + gn] = f2b(acc[i][j][r] + bj);
    }
  }
}

// ---------------- MFMA causal attention v3 ----------------
// grid (2, H, B), 128 threads (2 waves). Wave g owns q-chunk qc=2*qp+g.
// K staged [key][d]; V staged TRANSPOSED [d][key] so PV B-frags are b128.
// Q pre-scaled by log2(e)/8 in QKV GEMM. In-place output over q-slice.
// P relay is per-wave LDS (in-order LDS pipe) -> no barrier between P and PV.
__global__ __launch_bounds__(128) void attn_mfma(ushort* __restrict__ qkv) {
  __shared__ ushort lk[64 * 72];      // K chunk  [key][64+8]
  __shared__ ushort lvT[64 * 72];     // V^T      [d][64+8]
  __shared__ ushort lp[2 * 64 * 72];  // per-wave P [qrow][64+8]
  const int qp = blockIdx.x, h = blockIdx.y, b = blockIdx.z;
  const int tid = threadIdx.x;
  const int g = tid >> 6, lane = tid & 63;
  const int tr = lane & 15, tq = lane >> 4;
  const int qc = qp * 2 + g;
  const int q0 = qc << 6;
  ushort* myp = &lp[g * 64 * 72];

  bf16x8 qf[4][2];
#pragma unroll
  for (int i = 0; i < 4; ++i)
#pragma unroll
    for (int s = 0; s < 2; ++s)
      qf[i][s] = *(const bf16x8*)(qkv +
                                  (size_t)(b * 256 + q0 + i * 16 + tr) * 1536 +
                                  h * 64 + s * 32 + tq * 8);

  f32x4 o[4][4];
  float pl[4][4];
#pragma unroll
  for (int i = 0; i < 4; ++i)
#pragma unroll
    for (int j = 0; j < 4; ++j) {
      o[i][j] = (f32x4)(0.f);
      pl[i][j] = 0.f;
    }

  const int key = tid >> 1, half = tid & 1;
  const int cmax = qp * 2 + 1;
  for (int c = 0; c <= cmax; ++c) {
    __syncthreads();  // protect prior chunk's lk/lvT reads
    const ushort* gk =
        qkv + (size_t)(b * 256 + c * 64 + key) * 1536 + 512 + h * 64 + half * 32;
#pragma unroll
    for (int u = 0; u < 4; ++u)
      *(uint4*)&lk[key * 72 + half * 32 + u * 8] = *(const uint4*)(gk + u * 8);
    ushort vloc[32];
#pragma unroll
    for (int u = 0; u < 4; ++u)
      *(uint4*)&vloc[u * 8] = *(const uint4*)(gk + 512 + u * 8);
#pragma unroll
    for (int dd = 0; dd < 32; ++dd)
      lvT[(half * 32 + dd) * 72 + key] = vloc[dd];
    __syncthreads();

    if (c <= qc) {
      // S = Q . K^T
      f32x4 Sv[4][4];
#pragma unroll
      for (int i = 0; i < 4; ++i)
#pragma unroll
        for (int j = 0; j < 4; ++j) Sv[i][j] = (f32x4)(0.f);
      bf16x8 kf[4][2];
#pragma unroll
      for (int j = 0; j < 4; ++j)
#pragma unroll
        for (int s = 0; s < 2; ++s)
          kf[j][s] = *(const bf16x8*)&lk[(j * 16 + tr) * 72 + s * 32 + tq * 8];
#pragma unroll
      for (int i = 0; i < 4; ++i)
#pragma unroll
        for (int j = 0; j < 4; ++j) {
          Sv[i][j] = __builtin_amdgcn_mfma_f32_16x16x32_bf16(qf[i][0], kf[j][0],
                                                             Sv[i][j], 0, 0, 0);
          Sv[i][j] = __builtin_amdgcn_mfma_f32_16x16x32_bf16(qf[i][1], kf[j][1],
                                                             Sv[i][j], 0, 0, 0);
        }
      // exp2 (Q pre-scaled) + causal mask + partial rowsums + P -> own LDS
      const bool diag = (c == qc);
#pragma unroll
      for (int i = 0; i < 4; ++i)
#pragma unroll
        for (int j = 0; j < 4; ++j)
#pragma unroll
          for (int r = 0; r < 4; ++r) {
            float e = exp2f(Sv[i][j][r]);
            if (diag && (j * 16 + tr) > (i * 16 + tq * 4 + r)) e = 0.f;
            pl[i][r] += e;
            myp[(i * 16 + tq * 4 + r) * 72 + j * 16 + tr] =
                (ushort)(__float_as_uint(e) >> 16);  // trunc: P in [0,1]
          }
      // O += P . V  (same-wave LDS RAW: in-order DS pipe, no barrier)
#pragma unroll
      for (int s = 0; s < 2; ++s) {
        bf16x8 vf[4], af[4];
#pragma unroll
        for (int jn = 0; jn < 4; ++jn)
          vf[jn] = *(const bf16x8*)&lvT[(jn * 16 + tr) * 72 + s * 32 + tq * 8];
#pragma unroll
        for (int im = 0; im < 4; ++im)
          af[im] = *(const bf16x8*)&myp[(im * 16 + tr) * 72 + s * 32 + tq * 8];
#pragma unroll
        for (int im = 0; im < 4; ++im)
#pragma unroll
          for (int jn = 0; jn < 4; ++jn)
            o[im][jn] = __builtin_amdgcn_mfma_f32_16x16x32_bf16(af[im], vf[jn],
                                                                o[im][jn], 0, 0, 0);
      }
    }
  }

#pragma unroll
  for (int i = 0; i < 4; ++i)
#pragma unroll
    for (int r = 0; r < 4; ++r) {
      float v = pl[i][r];
      v += __shfl_xor(v, 1, 64);
      v += __shfl_xor(v, 2, 64);
      v += __shfl_xor(v, 4, 64);
      v += __shfl_xor(v, 8, 64);
      pl[i][r] = 1.f / v;
    }

#pragma unroll
  for (int i = 0; i < 4; ++i)
#pragma unroll
    for (int j = 0; j < 4; ++j)
#pragma unroll
      for (int r = 0; r < 4; ++r)
        qkv[(size_t)(b * 256 + q0 + i * 16 + tq * 4 + r) * 1536 + h * 64 +
            j * 16 + tr] = f2b(o[i][j][r] * pl[i][r]);
}

// ---- fused LN1+LN2: x = LN2(LN1(x + d1) + cavec16[b]) ---------------------
__global__ __launch_bounds__(256) void ln12_kernel(
    ushort* __restrict__ x16, const uint* __restrict__ d1,
    const uint* __restrict__ cavec, const float* __restrict__ s1,
    const float* __restrict__ b1, const float* __restrict__ s2,
    const float* __restrict__ b2p) {
  const int r = blockIdx.x, t = threadIdx.x;
  const int lane = t & 63, wv = t >> 6;
  uint* xr = (uint*)x16 + (size_t)r * 256;
  uint xu = xr[t];
  uint du = d1[(size_t)r * 768 + t];
  float v0 = blo(xu) + blo(du), v1 = bhi(xu) + bhi(du);
  __shared__ float redA[4][2], redB[4][2];
  float sm = v0 + v1, sq = v0 * v0 + v1 * v1;
#pragma unroll
  for (int o = 32; o > 0; o >>= 1) {
    sm += __shfl_xor(sm, o, 64);
    sq += __shfl_xor(sq, o, 64);
  }
  if (lane == 0) {
    redA[wv][0] = sm;
    redA[wv][1] = sq;
  }
  __syncthreads();
  sm = redA[0][0] + redA[1][0] + redA[2][0] + redA[3][0];
  sq = redA[0][1] + redA[1][1] + redA[2][1] + redA[3][1];
  float mean = sm * (1.f / 512.f);
  float var = sq * (1.f / 512.f) - mean * mean;
  float rs = rsqrtf(var + 1e-5f);
  float2 sa = ((const float2*)s1)[t];
  float2 ba = ((const float2*)b1)[t];
  uint cu = cavec[(size_t)(r >> 8) * 256 + t];
  float w0 = (v0 - mean) * rs * sa.x + ba.x + blo(cu);
  float w1 = (v1 - mean) * rs * sa.y + ba.y + bhi(cu);
  sm = w0 + w1;
  sq = w0 * w0 + w1 * w1;
#pragma unroll
  for (int o = 32; o > 0; o >>= 1) {
    sm += __shfl_xor(sm, o, 64);
    sq += __shfl_xor(sq, o, 64);
  }
  if (lane == 0) {
    redB[wv][0] = sm;
    redB[wv][1] = sq;
  }
  __syncthreads();
  sm = redB[0][0] + redB[1][0] + redB[2][0] + redB[3][0];
  sq = redB[0][1] + redB[1][1] + redB[2][1] + redB[3][1];
  mean = sm * (1.f / 512.f);
  var = sq * (1.f / 512.f) - mean * mean;
  rs = rsqrtf(var + 1e-5f);
  float2 sb = ((const float2*)s2)[t];
  float2 bb = ((const float2*)b2p)[t];
  float y0 = (w0 - mean) * rs * sb.x + bb.x;
  float y1 = (w1 - mean) * rs * sb.y + bb.y;
  xr[t] = pack2(y0, y1);
}

// -------- LayerNorm: x16 = bf16(LN(x16 + delta) * sc + bi), in place --------
__global__ __launch_bounds__(256) void ln_kernel(
    ushort* __restrict__ x16, const uint* __restrict__ delta, int DsU,
    const float* __restrict__ sc, const float* __restrict__ bi) {
  const int r = blockIdx.x, t = threadIdx.x;
  const int lane = t & 63, wv = t >> 6;
  uint* xr = (uint*)x16 + (size_t)r * 256;
  uint xu = xr[t];
  uint du = delta[(size_t)r * DsU + t];
  float v0 = blo(xu) + blo(du), v1 = bhi(xu) + bhi(du);
  float sm = v0 + v1, sq = v0 * v0 + v1 * v1;
#pragma unroll
  for (int o = 32; o > 0; o >>= 1) {
    sm += __shfl_xor(sm, o, 64);
    sq += __shfl_xor(sq, o, 64);
  }
  __shared__ float red[4][2];
  if (lane == 0) {
    red[wv][0] = sm;
    red[wv][1] = sq;
  }
  __syncthreads();
  sm = red[0][0] + red[1][0] + red[2][0] + red[3][0];
  sq = red[0][1] + red[1][1] + red[2][1] + red[3][1];
  float mean = sm * (1.f / 512.f);
  float var = sq * (1.f / 512.f) - mean * mean;
  float rs = rsqrtf(var + 1e-5f);
  float2 s2 = ((const float2*)sc)[t];
  float2 b2 = ((const float2*)bi)[t];
  float y0 = (v0 - mean) * rs * s2.x + b2.x;
  float y1 = (v1 - mean) * rs * s2.y + b2.y;
  xr[t] = pack2(y0, y1);
}

extern "C" void kernel_launch(void* const* d_in, const int* in_sizes, int n_in,
                              void* d_out, int out_size, void* d_ws,
                              size_t ws_size, hipStream_t stream) {
  (void)in_sizes; (void)n_in; (void)out_size; (void)ws_size;
  const float* z = (const float*)d_in[0];
  const int* tgt = (const int*)d_in[1];
  const float* emb = (const float*)d_in[2];
  const float* pos = (const float*)d_in[3];
  const float* projw = (const float*)d_in[4];
  const float* projb = (const float*)d_in[5];
  const float* saw = (const float*)d_in[6];
  const float* sab = (const float*)d_in[7];
  const float* saow = (const float*)d_in[8];
  const float* saob = (const float*)d_in[9];
  const float* caw = (const float*)d_in[10];
  const float* cab = (const float*)d_in[11];
  const float* caow = (const float*)d_in[12];
  const float* caob = (const float*)d_in[13];
  const float* ln1s = (const float*)d_in[14];
  const float* ln1b = (const float*)d_in[15];
  const float* ln2s = (const float*)d_in[16];
  const float* ln2b = (const float*)d_in[17];
  const float* ln3s = (const float*)d_in[18];
  const float* ln3b = (const float*)d_in[19];
  const float* ff1w = (const float*)d_in[20];
  const float* ff1b = (const float*)d_in[21];
  const float* ff2w = (const float*)d_in[22];
  const float* ff2b = (const float*)d_in[23];
  const float* fcw = (const float*)d_in[24];
  const float* fcb = (const float*)d_in[25];

  // workspace carve — TOTAL ~103 MiB:
  // [0,16M)    x16 bf16 residual
  // [16M,64M)  qkv 48M (attn in-place; out-proj delta in dead k-slice);
  //            FF phase: hbuf 32M + fdel 16M
  // [64M,66M)  bf16 smalls: z16(128x512) memv16(128x512) cav16(6x128x512)
  //            cavec16(6x128x512) — rows 64..127 are junk (M padded to 128)
  // [66M,~103M) bf16 weights (converted once per launch)
  char* w8 = (char*)d_ws;
  ushort* x16 = (ushort*)w8;
  ushort* qkv = (ushort*)(w8 + (16u << 20));
  ushort* hbuf = qkv;
  ushort* fdel = (ushort*)(w8 + (48u << 20));
  ushort* z16 = (ushort*)(w8 + (64u << 20));
  ushort* memv16 = z16 + 128 * 512;
  ushort* cav16 = memv16 + 128 * 512;
  ushort* cavec16 = cav16 + (size_t)L_ * 128 * 512;
  ushort* wsaw = (ushort*)(w8 + (66u << 20));
  ushort* wsaow = wsaw + (size_t)L_ * 1536 * 512;
  ushort* wff1 = wsaow + (size_t)L_ * 512 * 512;
  ushort* wff2 = wff1 + (size_t)L_ * 2048 * 512;
  ushort* wfcw = wff2 + (size_t)L_ * 512 * 2048;

  // one-time weight conversions (fp32 -> bf16)
  conv_kernel<<<(L_ * 1536 * 512) / 512, 256, 0, stream>>>(saw, wsaw);
  conv_kernel<<<(L_ * 512 * 512) / 512, 256, 0, stream>>>(saow, wsaow);
  conv_kernel<<<(L_ * 2048 * 512) / 512, 256, 0, stream>>>(ff1w, wff1);
  conv_kernel<<<(L_ * 512 * 2048) / 512, 256, 0, stream>>>(ff2w, wff2);
  conv_kernel<<<(V_ * 512) / 512, 256, 0, stream>>>(fcw, wfcw);
  conv_kernel<<<(B_ * 512) / 512, 256, 0, stream>>>(z, z16);

  embed_kernel<<<16384, 256, 0, stream>>>(tgt, emb, pos, x16);

  // collapsed cross-attention (kv len 1) via padded-M MFMA, all batched:
  // memv16 = z16 . projw^T + projb
  gemm_btf<<<dim3(4, 1, 1), 256, 0, stream>>>(z16, 0, projw, 0, projb, 0,
                                              memv16, 0, 512, 512, 512, 512, 512);
  // cav16[l] = memv16 . Wv_l^T + bv_l
  gemm_btf<<<dim3(4, 1, L_), 256, 0, stream>>>(
      memv16, 0, caw + 1024 * 512, (long)1536 * 512, cab + 1024, 1536, cav16,
      (long)128 * 512, 512, 512, 512, 512, 512);
  // cavec16[l] = cav16[l] . Wo_l^T + bo_l
  gemm_btf<<<dim3(4, 1, L_), 256, 0, stream>>>(
      cav16, (long)128 * 512, caow, (long)512 * 512, caob, 512, cavec16,
      (long)128 * 512, 512, 512, 512, 512, 512);

  for (int i = 0; i < L_; ++i) {
    // QKV (+ Q pre-scale): qkv = x16 . sa_w^T + sa_b
    gemm_bt<4><<<dim3(12, 128), 256, 0, stream>>>(
        x16, wsaw + (size_t)i * 1536 * 512, sab + i * 1536, qkv, 1536, 512, 512,
        512, 1536);
    attn_mfma<<<dim3(2, H_, B_), 128, 0, stream>>>(qkv);
    // out-proj -> dead k-slice
    gemm_bt<0><<<dim3(4, 128), 256, 0, stream>>>(
        qkv, wsaow + (size_t)i * 512 * 512, saob + i * 512, qkv + 512, 512, 512,
        1536, 512, 1536);
    // fused LN1 + cross-attn add + LN2
    ln12_kernel<<<16384, 256, 0, stream>>>(
        x16, (const uint*)(qkv + 512), (const uint*)(cavec16 + (size_t)i * 128 * 512),
        ln1s + i * 512, ln1b + i * 512, ln2s + i * 512, ln2b + i * 512);
    // FFN split into two DFF=1024 chunks
    gemm_bt<1><<<dim3(8, 128), 256, 0, stream>>>(
        x16, wff1 + (size_t)i * 2048 * 512, ff1b + i * 2048, hbuf, 1024, 512,
        512, 512, 1024);
    gemm_bt<0><<<dim3(4, 128), 256, 0, stream>>>(
        hbuf, wff2 + (size_t)i * 512 * 2048, ff2b + i * 512, fdel, 512, 1024,
        1024, 2048, 512);
    gemm_bt<1><<<dim3(8, 128), 256, 0, stream>>>(
        x16, wff1 + ((size_t)i * 2048 + 1024) * 512, ff1b + i * 2048 + 1024,
        hbuf, 1024, 512, 512, 512, 1024);
    gemm_bt<2><<<dim3(4, 128), 256, 0, stream>>>(
        hbuf, wff2 + (size_t)i * 512 * 2048 + 1024, (const float*)0, fdel, 512,
        1024, 1024, 2048, 512);
    ln_kernel<<<16384, 256, 0, stream>>>(x16, (const uint*)fdel, 256,
                                         ln3s + i * 512, ln3b + i * 512);
  }
  gemm_bt<3><<<dim3(1, 128), 256, 0, stream>>>(x16, wfcw, fcb, d_out, 128, 512,
                                               512, 512, 128);
}